// Round 3
// baseline (301.213 us; speedup 1.0000x reference)
//
#include <hip/hip_runtime.h>
#include <stdint.h>

typedef __attribute__((ext_vector_type(8))) short  short8;   // 8 bf16 = 4 VGPR MFMA frag
typedef __attribute__((ext_vector_type(4))) float  f32x4;    // MFMA accumulator
typedef __attribute__((ext_vector_type(4))) unsigned short us4;

static __device__ __forceinline__ unsigned short f2bf(float x) {
  unsigned u = __builtin_bit_cast(unsigned, x);
  u += 0x7FFFu + ((u >> 16) & 1u);          // round-to-nearest-even
  return (unsigned short)(u >> 16);
}

static __device__ __forceinline__ unsigned cvt_pk_bf16(float lo, float hi) {
  unsigned r;
  asm("v_cvt_pk_bf16_f32 %0, %1, %2" : "=v"(r) : "v"(lo), "v"(hi));
  return r;
}

// max with DPP-shuffled self (reduction over 16-lane row)
template <int CTRL>
static __device__ __forceinline__ float maxdpp(float v) {
  int o = __builtin_amdgcn_update_dpp(0, __builtin_bit_cast(int, v), CTRL, 0xf, 0xf, false);
  return fmaxf(v, __builtin_bit_cast(float, o));
}
static __device__ __forceinline__ float rowmax16(float v) {
  v = maxdpp<0xB1>(v);    // quad_perm [1,0,3,2]  (xor 1)
  v = maxdpp<0x4E>(v);    // quad_perm [2,3,0,1]  (xor 2)
  v = maxdpp<0x141>(v);   // row_half_mirror      (xor 4 after quads uniform)
  v = maxdpp<0x140>(v);   // row_mirror           (xor 8 after halves uniform)
  return v;
}

// ---------------------------------------------------------------- fp32 -> bf16
__global__ __launch_bounds__(256) void cvt_kernel(const float* __restrict__ in,
                                                  unsigned short* __restrict__ out,
                                                  int n4) {
  int i = blockIdx.x * blockDim.x + threadIdx.x;
  int stride = gridDim.x * blockDim.x;
  for (; i < n4; i += stride) {
    f32x4 v = *((const f32x4*)in + i);
    us4 o = { f2bf(v[0]), f2bf(v[1]), f2bf(v[2]), f2bf(v[3]) };
    *((us4*)out + i) = o;
  }
}

// --------------------------------------------- pmask -> f32 bias + 64-key tile flags
__global__ __launch_bounds__(64) void bias_kernel(const int* __restrict__ pm,
                                                  float* __restrict__ bias,
                                                  int* __restrict__ flags) {
  int j = blockIdx.x;                       // (b, kt) pair, 128 total
  int i = j * 64 + threadIdx.x;
  int z = pm[i];
  bias[i] = (z == 0) ? -1.0e9f : 0.0f;
  unsigned long long m = __ballot(z == 0);
  if (threadIdx.x == 0) flags[j] = (m != 0ull) ? 1 : 0;
}

// ------------------------------------------------------- async global->LDS 16B
static __device__ __forceinline__ void g2l16(const void* g, void* l) {
  __builtin_amdgcn_global_load_lds(
      (const __attribute__((address_space(1))) void*)g,
      (__attribute__((address_space(3))) void*)l, 16, 0, 0);
}

// ---------------------------------------------------------------- NT GEMM
// C[m][n] = sum_k A[m][k] * W[n][k].  A: MxK bf16, W: NxK bf16.
// BM=BN=128, BK=32, 256 threads = 4 waves (2x2), 64x64 per wave.
// MODE 0: bf16 out (scaled), row-major. MODE 1: bf16 out transposed for V.
// MODE 2: f32 out row-major.
template <int MODE>
__global__ __launch_bounds__(256) void gemm_nt(const unsigned short* __restrict__ A,
                                               const unsigned short* __restrict__ W,
                                               void* __restrict__ outp,
                                               int M, int N, int K, float scale) {
  __shared__ unsigned short Alds[128 * 32];
  __shared__ unsigned short Blds[128 * 32];
  const int tid  = threadIdx.x;
  const int lane = tid & 63;
  const int w    = tid >> 6;
  const int g    = lane >> 4;
  const int li   = lane & 15;
  const int m0 = blockIdx.y * 128;
  const int n0 = blockIdx.x * 128;
  const int wm = (w >> 1) * 64;
  const int wn = (w & 1) * 64;

  int aoff[4], boff[4];
#pragma unroll
  for (int mi = 0; mi < 4; ++mi) {
    int row = wm + mi * 16 + li;
    aoff[mi] = row * 32 + (g ^ ((row >> 1) & 3)) * 8;
  }
#pragma unroll
  for (int ni = 0; ni < 4; ++ni) {
    int col = wn + ni * 16 + li;
    boff[ni] = col * 32 + (g ^ ((col >> 1) & 3)) * 8;
  }

  const int s1 = tid, s2 = 256 + tid;
  const int r1 = s1 >> 2, gc1 = (s1 & 3) ^ ((r1 >> 1) & 3);
  const int r2 = s2 >> 2, gc2 = (s2 & 3) ^ ((r2 >> 1) & 3);
  const unsigned short* gA1 = A + (size_t)(m0 + r1) * K + gc1 * 8;
  const unsigned short* gA2 = A + (size_t)(m0 + r2) * K + gc2 * 8;
  const unsigned short* gB1 = W + (size_t)(n0 + r1) * K + gc1 * 8;
  const unsigned short* gB2 = W + (size_t)(n0 + r2) * K + gc2 * 8;
  unsigned short* lA1 = &Alds[w * 512];
  unsigned short* lA2 = &Alds[2048 + w * 512];
  unsigned short* lB1 = &Blds[w * 512];
  unsigned short* lB2 = &Blds[2048 + w * 512];

  f32x4 acc[4][4] = {};

  const int nkt = K >> 5;
#pragma unroll 1
  for (int kt = 0; kt < nkt; ++kt) {
    g2l16(gA1, lA1); g2l16(gA2, lA2);
    g2l16(gB1, lB1); g2l16(gB2, lB2);
    gA1 += 32; gA2 += 32; gB1 += 32; gB2 += 32;
    asm volatile("s_waitcnt vmcnt(0)" ::: "memory");
    __syncthreads();
    short8 af[4], bf[4];
#pragma unroll
    for (int mi = 0; mi < 4; ++mi) af[mi] = *(const short8*)&Alds[aoff[mi]];
#pragma unroll
    for (int ni = 0; ni < 4; ++ni) bf[ni] = *(const short8*)&Blds[boff[ni]];
#pragma unroll
    for (int mi = 0; mi < 4; ++mi)
#pragma unroll
      for (int ni = 0; ni < 4; ++ni)
        acc[mi][ni] = __builtin_amdgcn_mfma_f32_16x16x32_bf16(af[mi], bf[ni], acc[mi][ni], 0, 0, 0);
    __syncthreads();
  }

  if (MODE == 0) {
    unsigned short* C = (unsigned short*)outp;
#pragma unroll
    for (int mi = 0; mi < 4; ++mi) {
      int mb = m0 + wm + mi * 16 + g * 4;
#pragma unroll
      for (int ni = 0; ni < 4; ++ni) {
        int n = n0 + wn + ni * 16 + li;
#pragma unroll
        for (int r = 0; r < 4; ++r)
          C[(size_t)(mb + r) * N + n] = f2bf(acc[mi][ni][r] * scale);
      }
    }
  } else if (MODE == 1) {
    unsigned short* C = (unsigned short*)outp;   // (B*1024) x 2048
#pragma unroll
    for (int mi = 0; mi < 4; ++mi) {
      int mb = m0 + wm + mi * 16 + g * 4;
      int bb = mb >> 11, s = mb & 2047;
#pragma unroll
      for (int ni = 0; ni < 4; ++ni) {
        int n = n0 + wn + ni * 16 + li;
        us4 pk = { f2bf(acc[mi][ni][0]), f2bf(acc[mi][ni][1]),
                   f2bf(acc[mi][ni][2]), f2bf(acc[mi][ni][3]) };
        *(us4*)&C[(size_t)(bb * 1024 + n) * 2048 + s] = pk;
      }
    }
  } else {
    float* C = (float*)outp;
#pragma unroll
    for (int mi = 0; mi < 4; ++mi) {
      int mb = m0 + wm + mi * 16 + g * 4;
#pragma unroll
      for (int ni = 0; ni < 4; ++ni) {
        int n = n0 + wn + ni * 16 + li;
#pragma unroll
        for (int r = 0; r < 4; ++r)
          C[(size_t)(mb + r) * N + n] = acc[mi][ni][r];
      }
    }
  }
}

// ---------------------------------------------------------------- attention v3
// Block = 512 threads (8 waves), one 128-row q-tile of one (b,h). Wave w owns
// 16 q rows. Q pre-scaled by 0.125*log2(e) (folded into Q projection).
// K/V 64-key tiles double-buffered in LDS via global_load_lds (XOR-swizzled
// source), counted vmcnt(2); DPP row-max; defer-max (THR=8); cvt_pk P->bf16.
__global__ __launch_bounds__(512, 6) void attn_kernel(const unsigned short* __restrict__ Qp,
                                                      const unsigned short* __restrict__ Kp,
                                                      const unsigned short* __restrict__ Vt,
                                                      const float* __restrict__ bias,
                                                      const int* __restrict__ flags,
                                                      unsigned short* __restrict__ att) {
  __shared__ unsigned short Klds[2][64 * 64];
  __shared__ unsigned short Vlds[2][64 * 64];
  __shared__ unsigned short Plds[8][16 * 72];

  const int tid = threadIdx.x, lane = tid & 63, w = tid >> 6;
  const int g = lane >> 4, li = lane & 15;
  const int bh = blockIdx.y, b = bh >> 4, h = bh & 15;
  const int t = 15 - blockIdx.x;            // long tiles dispatched first
  const int nkt = 2 * t + 2;
  const int qw = t * 128 + w * 16;
  const int ktd = (qw + 15) >> 6;           // diagonal iteration for this wave

  const int srow = tid >> 3, swc = (tid & 7) ^ (srow & 7);
  const unsigned short* Ksrc = Kp + (size_t)(b * 2048 + srow) * 1024 + h * 64 + swc * 8;
  const unsigned short* Vsrc = Vt + (size_t)(b * 1024 + h * 64 + srow) * 2048 + swc * 8;

  int foff[2][4];
#pragma unroll
  for (int ks = 0; ks < 2; ++ks)
#pragma unroll
    for (int i = 0; i < 4; ++i)
      foff[ks][i] = (i * 16 + li) * 64 + (((ks * 4 + g) ^ (li & 7)) * 8);

  unsigned short* Pl = &Plds[w][0];
  const float* bbase = bias + b * 2048 + li;
  const int*   fbase = flags + b * 32;

  short8 ones;
#pragma unroll
  for (int j = 0; j < 8; ++j) ones[j] = (short)0x3F80;  // bf16 1.0

  short8 qfr[2];
#pragma unroll
  for (int ks = 0; ks < 2; ++ks)
    qfr[ks] = *(const short8*)&Qp[((size_t)(b * 2048 + qw + li)) * 1024 +
                                  h * 64 + ks * 32 + g * 8];

  f32x4 acco[4] = {};
  f32x4 lacc = {};
  float mrow[4] = {-3.0e38f, -3.0e38f, -3.0e38f, -3.0e38f};
  const f32x4 Z = {0.f, 0.f, 0.f, 0.f};

  g2l16(Ksrc, &Klds[0][w * 512]);
  g2l16(Vsrc, &Vlds[0][w * 512]);

  int buf = 0;
#pragma unroll 1
  for (int it = 0; it < nkt; ++it) {
    if (it + 1 < nkt) {
      g2l16(Ksrc + (size_t)(it + 1) * 65536, &Klds[buf ^ 1][w * 512]);
      g2l16(Vsrc + (size_t)(it + 1) * 64,    &Vlds[buf ^ 1][w * 512]);
      asm volatile("s_waitcnt vmcnt(2)" ::: "memory");
    } else {
      asm volatile("s_waitcnt vmcnt(0)" ::: "memory");
    }
    __builtin_amdgcn_s_barrier();

    if (it <= ktd) {
      // ---- QK^T (Q pre-scaled; scores directly in log2 domain)
      f32x4 s[4];
#pragma unroll
      for (int ni = 0; ni < 4; ++ni) {
        short8 kf = *(const short8*)&Klds[buf][foff[0][ni]];
        s[ni] = __builtin_amdgcn_mfma_f32_16x16x32_bf16(qfr[0], kf, Z, 0, 0, 0);
      }
#pragma unroll
      for (int ni = 0; ni < 4; ++ni) {
        short8 kf = *(const short8*)&Klds[buf][foff[1][ni]];
        s[ni] = __builtin_amdgcn_mfma_f32_16x16x32_bf16(qfr[1], kf, s[ni], 0, 0, 0);
      }
      // ---- padding bias (skipped when this 64-key tile has no padding)
      if (fbase[it]) {
#pragma unroll
        for (int ni = 0; ni < 4; ++ni) {
          float bv = bbase[it * 64 + ni * 16];
#pragma unroll
          for (int r = 0; r < 4; ++r) s[ni][r] += bv;
        }
      }
      // ---- causal mask (only on the diagonal iteration)
      if (it == ktd) {
        const int q0 = qw + g * 4;
#pragma unroll
        for (int ni = 0; ni < 4; ++ni) {
          const int key = it * 64 + ni * 16 + li;
#pragma unroll
          for (int r = 0; r < 4; ++r)
            if (key > q0 + r) s[ni][r] = -1.0e9f;
        }
      }
      // ---- tile max per row (in-lane + DPP over 16 key-lanes)
      float tm[4];
#pragma unroll
      for (int r = 0; r < 4; ++r)
        tm[r] = rowmax16(fmaxf(fmaxf(s[0][r], s[1][r]), fmaxf(s[2][r], s[3][r])));
      // ---- defer-max: rescale only when max grew by > 8 (log2 units)
      int need = 0;
#pragma unroll
      for (int r = 0; r < 4; ++r) need |= (tm[r] > mrow[r] + 8.0f) ? 1 : 0;
      if (__any(need)) {
#pragma unroll
        for (int r = 0; r < 4; ++r) {
          const float mn = fmaxf(mrow[r], tm[r]);
          const float al = exp2f(mrow[r] - mn);
          mrow[r] = mn;
          lacc[r] *= al;
#pragma unroll
          for (int df = 0; df < 4; ++df) acco[df][r] *= al;
        }
      }
      // ---- p = exp2(s - m) -> bf16 (cvt_pk) -> LDS (stride 72)
#pragma unroll
      for (int ni = 0; ni < 4; ++ni) {
#pragma unroll
        for (int h2 = 0; h2 < 2; ++h2) {
          float lo = exp2f(s[ni][2 * h2]     - mrow[2 * h2]);
          float hi = exp2f(s[ni][2 * h2 + 1] - mrow[2 * h2 + 1]);
          unsigned pk = cvt_pk_bf16(lo, hi);
          Pl[(g * 4 + 2 * h2)     * 72 + ni * 16 + li] = (unsigned short)pk;
          Pl[(g * 4 + 2 * h2 + 1) * 72 + ni * 16 + li] = (unsigned short)(pk >> 16);
        }
      }
      // ---- PV (+ ones column for row-sum l)
#pragma unroll
      for (int ks = 0; ks < 2; ++ks) {
        const short8 pa = *(const short8*)&Pl[li * 72 + ks * 32 + g * 8];
        short8 vf[4];
#pragma unroll
        for (int df = 0; df < 4; ++df) vf[df] = *(const short8*)&Vlds[buf][foff[ks][df]];
#pragma unroll
        for (int df = 0; df < 4; ++df)
          acco[df] = __builtin_amdgcn_mfma_f32_16x16x32_bf16(pa, vf[df], acco[df], 0, 0, 0);
        lacc = __builtin_amdgcn_mfma_f32_16x16x32_bf16(pa, ones, lacc, 0, 0, 0);
      }
    }
    __builtin_amdgcn_s_barrier();
    buf ^= 1;
  }

  // ---- epilogue
  float inv[4];
#pragma unroll
  for (int r = 0; r < 4; ++r) inv[r] = 1.0f / lacc[r];
  const int qb0 = qw + g * 4;
#pragma unroll
  for (int df = 0; df < 4; ++df) {
    const int d = h * 64 + df * 16 + li;
#pragma unroll
    for (int r = 0; r < 4; ++r)
      att[(size_t)(b * 2048 + qb0 + r) * 1024 + d] = f2bf(acco[df][r] * inv[r]);
  }
}

// ---------------------------------------------------------------- launch
extern "C" void kernel_launch(void* const* d_in, const int* in_sizes, int n_in,
                              void* d_out, int out_size, void* d_ws, size_t ws_size,
                              hipStream_t stream) {
  const float* q_raw  = (const float*)d_in[0];
  const float* kv_raw = (const float*)d_in[1];
  const int*   pmask  = (const int*)d_in[2];
  const float* Wq = (const float*)d_in[3];
  const float* Wk = (const float*)d_in[4];
  const float* Wv = (const float*)d_in[5];
  const float* Wo = (const float*)d_in[6];
  float* out = (float*)d_out;

  const size_t NEL = 8388608;   // B*S*D
  const size_t WEL = 1048576;   // D*D
  unsigned short* ws   = (unsigned short*)d_ws;
  unsigned short* qbf  = ws;              // reused as att after projections
  unsigned short* kvbf = qbf + NEL;
  unsigned short* wbf  = kvbf + NEL;      // Wq,Wk,Wv,Wo bf16 back-to-back
  unsigned short* Qp   = wbf + 4 * WEL;
  unsigned short* Kp   = Qp + NEL;
  unsigned short* Vtp  = Kp + NEL;        // (B,H,DH,S) transposed V
  float*          bias = (float*)(Vtp + NEL);
  int*            flags = (int*)(bias + 8192);
  unsigned short* att  = qbf;             // alias (qbf dead after projections)

  const float sc = 0.125f * 1.44269504088896340736f;  // 1/sqrt(DH) * log2(e)

  cvt_kernel<<<2048, 256, 0, stream>>>(q_raw,  qbf,  (int)(NEL / 4));
  cvt_kernel<<<2048, 256, 0, stream>>>(kv_raw, kvbf, (int)(NEL / 4));
  cvt_kernel<<<256, 256, 0, stream>>>(Wq, wbf,           (int)(WEL / 4));
  cvt_kernel<<<256, 256, 0, stream>>>(Wk, wbf + WEL,     (int)(WEL / 4));
  cvt_kernel<<<256, 256, 0, stream>>>(Wv, wbf + 2 * WEL, (int)(WEL / 4));
  cvt_kernel<<<256, 256, 0, stream>>>(Wo, wbf + 3 * WEL, (int)(WEL / 4));
  bias_kernel<<<128, 64, 0, stream>>>(pmask, bias, flags);

  dim3 gg(8, 64);  // N/128, M/128
  gemm_nt<0><<<gg, 256, 0, stream>>>(qbf,  wbf,           (void*)Qp,  8192, 1024, 1024, sc);
  gemm_nt<0><<<gg, 256, 0, stream>>>(kvbf, wbf + WEL,     (void*)Kp,  8192, 1024, 1024, 1.0f);
  gemm_nt<1><<<gg, 256, 0, stream>>>(kvbf, wbf + 2 * WEL, (void*)Vtp, 8192, 1024, 1024, 1.0f);

  attn_kernel<<<dim3(16, 64), 512, 0, stream>>>(Qp, Kp, Vtp, bias, flags, att);

  gemm_nt<2><<<gg, 256, 0, stream>>>(att, wbf + 3 * WEL, (void*)out, 8192, 1024, 1024, 1.0f);
}